// Round 1
// baseline (475.933 us; speedup 1.0000x reference)
//
#include <hip/hip_runtime.h>
#include <hip/hip_bf16.h>

// Problem constants
#define BATCH 8
#define T 8192
#define IN_F 128
#define OUT_F 128
#define STATE_F 256
#define CHUNK 128          // scan chunk length
#define NCHUNK 64          // T / CHUNK
#define ROWS 65536         // BATCH*T

// ---------------------------------------------------------------------------
// K0: lampow[j][n] = Lambda[n]^(j+1), j in [0,128)
__global__ void k0_lampow(const float* __restrict__ nu_log,
                          const float* __restrict__ theta_log,
                          float2* __restrict__ lampow) {
    int n = threadIdx.x;
    float lm = expf(-expf(nu_log[n]));
    float th = expf(theta_log[n]);
    float lr = lm * cosf(th), li = lm * sinf(th);
    float pr = lr, pi = li;
    for (int j = 0; j < CHUNK; ++j) {
        lampow[j * STATE_F + n] = make_float2(pr, pi);
        float t = fmaf(pr, lr, -pi * li);
        pi = fmaf(pr, li, pi * lr);
        pr = t;
    }
}

// ---------------------------------------------------------------------------
// K1: states[row][n] = gamma[n] * (x[row] . Bc[n])   (complex, float2 layout)
// 16 rows per block, 256 threads (one per n).
__global__ __launch_bounds__(256) void k1_bu(const float* __restrict__ x,
                                             const float* __restrict__ B_re,
                                             const float* __restrict__ B_im,
                                             const float* __restrict__ gamma_log,
                                             float2* __restrict__ states) {
    __shared__ float xs[16 * IN_F];
    int tid = threadIdx.x;
    size_t row0 = (size_t)blockIdx.x * 16;
    // stage 16 contiguous x rows (2048 floats)
    const float4* xsrc = (const float4*)(x + row0 * IN_F);
    float4* xd = (float4*)xs;
    xd[tid] = xsrc[tid];
    xd[tid + 256] = xsrc[tid + 256];
    __syncthreads();

    int n = tid;
    float g = expf(gamma_log[n]);
    float accr[16], acci[16];
#pragma unroll
    for (int r = 0; r < 16; ++r) { accr[r] = 0.f; acci[r] = 0.f; }

    const float4* br4 = (const float4*)(B_re + n * IN_F);
    const float4* bi4 = (const float4*)(B_im + n * IN_F);
#pragma unroll 2
    for (int k4 = 0; k4 < IN_F / 4; ++k4) {
        float4 br = br4[k4], bi = bi4[k4];
#pragma unroll
        for (int r = 0; r < 16; ++r) {
            const float4 xv = *(const float4*)&xs[r * IN_F + k4 * 4];
            float ar = accr[r], ai = acci[r];
            ar = fmaf(xv.x, br.x, ar); ai = fmaf(xv.x, bi.x, ai);
            ar = fmaf(xv.y, br.y, ar); ai = fmaf(xv.y, bi.y, ai);
            ar = fmaf(xv.z, br.z, ar); ai = fmaf(xv.z, bi.z, ai);
            ar = fmaf(xv.w, br.w, ar); ai = fmaf(xv.w, bi.w, ai);
            accr[r] = ar; acci[r] = ai;
        }
    }
    float2* sp = states + row0 * STATE_F + n;
#pragma unroll
    for (int r = 0; r < 16; ++r)
        sp[(size_t)r * STATE_F] = make_float2(accr[r] * g, acci[r] * g);
}

// ---------------------------------------------------------------------------
// K2a: in-place local scan of each chunk (zero initial state), record ends.
// grid = BATCH*NCHUNK blocks, 256 threads (one per n).
__global__ __launch_bounds__(256) void k2a_scan(const float* __restrict__ nu_log,
                                                const float* __restrict__ theta_log,
                                                float2* __restrict__ states,
                                                float2* __restrict__ ends) {
    int n = threadIdx.x;
    int b = blockIdx.x >> 6, c = blockIdx.x & 63;
    float lm = expf(-expf(nu_log[n]));
    float th = expf(theta_log[n]);
    float lr = lm * cosf(th), li = lm * sinf(th);
    float sr = 0.f, si = 0.f;
    float2* p = states + (((size_t)b * T + (size_t)c * CHUNK) * STATE_F + n);
#pragma unroll 1
    for (int j = 0; j < CHUNK; j += 4) {
        float2 b0 = p[0], b1 = p[STATE_F], b2 = p[2 * STATE_F], b3 = p[3 * STATE_F];
        float nr, ni;
        nr = fmaf(lr, sr, fmaf(-li, si, b0.x)); ni = fmaf(lr, si, fmaf(li, sr, b0.y)); sr = nr; si = ni; b0 = make_float2(sr, si);
        nr = fmaf(lr, sr, fmaf(-li, si, b1.x)); ni = fmaf(lr, si, fmaf(li, sr, b1.y)); sr = nr; si = ni; b1 = make_float2(sr, si);
        nr = fmaf(lr, sr, fmaf(-li, si, b2.x)); ni = fmaf(lr, si, fmaf(li, sr, b2.y)); sr = nr; si = ni; b2 = make_float2(sr, si);
        nr = fmaf(lr, sr, fmaf(-li, si, b3.x)); ni = fmaf(lr, si, fmaf(li, sr, b3.y)); sr = nr; si = ni; b3 = make_float2(sr, si);
        p[0] = b0; p[STATE_F] = b1; p[2 * STATE_F] = b2; p[3 * STATE_F] = b3;
        p += 4 * STATE_F;
    }
    ends[((size_t)(b * NCHUNK + c)) * STATE_F + n] = make_float2(sr, si);
}

// ---------------------------------------------------------------------------
// K2b: scan over chunk-final states: S_c = Lambda^CHUNK * S_{c-1} + E_c  (in place)
// grid = BATCH blocks, 256 threads.
__global__ void k2b_chain(const float* __restrict__ nu_log,
                          const float* __restrict__ theta_log,
                          float2* __restrict__ ends) {
    int n = threadIdx.x;
    int b = blockIdx.x;
    float lm = expf(-expf(nu_log[n]));
    float th = expf(theta_log[n]);
    float lr = lm * cosf(th), li = lm * sinf(th);
    float Lr = lr, Li = li;          // Lambda^1
    for (int j = 1; j < CHUNK; ++j) { // -> Lambda^CHUNK
        float t = fmaf(Lr, lr, -Li * li);
        Li = fmaf(Lr, li, Li * lr);
        Lr = t;
    }
    float sr = 0.f, si = 0.f;
    float2* p = ends + (size_t)b * NCHUNK * STATE_F + n;
    for (int c = 0; c < NCHUNK; ++c) {
        float2 e = p[(size_t)c * STATE_F];
        float nr = fmaf(Lr, sr, fmaf(-Li, si, e.x));
        float ni = fmaf(Lr, si, fmaf(Li, sr, e.y));
        sr = nr; si = ni;
        p[(size_t)c * STATE_F] = make_float2(sr, si);
    }
}

// ---------------------------------------------------------------------------
// K3: fused cross-chunk fixup + output projection:
// out[row][o] = Re( (local[row] + Lam^(j+1)*carry) . Cc[o] ) + x[row].D[o]
// 16 rows/block, 256 threads: tid -> (o = tid&127, h = tid>>7 splits K).
__global__ __launch_bounds__(256) void k3_out(const float* __restrict__ x,
                                              const float* __restrict__ C_re,
                                              const float* __restrict__ C_im,
                                              const float* __restrict__ D,
                                              const float2* __restrict__ states,
                                              const float2* __restrict__ ends,
                                              const float2* __restrict__ lampow,
                                              float* __restrict__ out) {
    __shared__ float sre[16][STATE_F];
    __shared__ float sim_[16][STATE_F];
    __shared__ float xs[16 * IN_F];
    __shared__ float part[16][OUT_F];

    int tid = threadIdx.x;
    size_t row0 = (size_t)blockIdx.x * 16;
    int b = (int)(row0 >> 13);       // /T
    int t0 = (int)(row0 & (T - 1));
    int c = t0 >> 7;                 // chunk index
    int j0 = t0 & (CHUNK - 1);       // t_loc of first row (multiple of 16)

    {   // stage states (+ cross-chunk fixup) and x tile
        int n = tid;
        float cr = 0.f, ci = 0.f;
        if (c > 0) {
            float2 cy = ends[((size_t)(b * NCHUNK + c - 1)) * STATE_F + n];
            cr = cy.x; ci = cy.y;
        }
        const float2* sp = states + row0 * STATE_F + n;
#pragma unroll
        for (int r = 0; r < 16; ++r) {
            float2 s = sp[(size_t)r * STATE_F];
            if (c > 0) {
                float2 pw = lampow[(j0 + r) * STATE_F + n];
                s.x = fmaf(pw.x, cr, fmaf(-pw.y, ci, s.x));
                s.y = fmaf(pw.x, ci, fmaf(pw.y, cr, s.y));
            }
            sre[r][n] = s.x;
            sim_[r][n] = s.y;
        }
        const float4* xsrc = (const float4*)(x + row0 * IN_F);
        float4* xd = (float4*)xs;
        xd[tid] = xsrc[tid];
        xd[tid + 256] = xsrc[tid + 256];
    }
    __syncthreads();

    int o = tid & (OUT_F - 1), h = tid >> 7;
    float acc[16];
#pragma unroll
    for (int r = 0; r < 16; ++r) acc[r] = 0.f;

    // C part: this half covers n in [h*128, h*128+128)
    const float4* crp = (const float4*)(C_re + o * STATE_F + h * 128);
    const float4* cip = (const float4*)(C_im + o * STATE_F + h * 128);
#pragma unroll 2
    for (int k4 = 0; k4 < 32; ++k4) {
        float4 cr = crp[k4], ci = cip[k4];
#pragma unroll
        for (int r = 0; r < 16; ++r) {
            const float4 s4 = *(const float4*)&sre[r][h * 128 + k4 * 4];
            const float4 m4 = *(const float4*)&sim_[r][h * 128 + k4 * 4];
            float a = acc[r];
            a = fmaf(s4.x, cr.x, a); a = fmaf(-m4.x, ci.x, a);
            a = fmaf(s4.y, cr.y, a); a = fmaf(-m4.y, ci.y, a);
            a = fmaf(s4.z, cr.z, a); a = fmaf(-m4.z, ci.z, a);
            a = fmaf(s4.w, cr.w, a); a = fmaf(-m4.w, ci.w, a);
            acc[r] = a;
        }
    }
    // D part: this half covers i in [h*64, h*64+64)
    const float4* dp = (const float4*)(D + o * IN_F + h * 64);
#pragma unroll 2
    for (int k4 = 0; k4 < 16; ++k4) {
        float4 dv = dp[k4];
#pragma unroll
        for (int r = 0; r < 16; ++r) {
            const float4 xv = *(const float4*)&xs[r * IN_F + h * 64 + k4 * 4];
            float a = acc[r];
            a = fmaf(xv.x, dv.x, a); a = fmaf(xv.y, dv.y, a);
            a = fmaf(xv.z, dv.z, a); a = fmaf(xv.w, dv.w, a);
            acc[r] = a;
        }
    }

    if (h == 1) {
#pragma unroll
        for (int r = 0; r < 16; ++r) part[r][o] = acc[r];
    }
    __syncthreads();
    if (h == 0) {
#pragma unroll
        for (int r = 0; r < 16; ++r)
            out[(row0 + r) * OUT_F + o] = acc[r] + part[r][o];
    }
}

// ---------------------------------------------------------------------------
extern "C" void kernel_launch(void* const* d_in, const int* in_sizes, int n_in,
                              void* d_out, int out_size, void* d_ws, size_t ws_size,
                              hipStream_t stream) {
    const float* x         = (const float*)d_in[0];
    const float* nu_log    = (const float*)d_in[1];
    const float* theta_log = (const float*)d_in[2];
    const float* gamma_log = (const float*)d_in[3];
    const float* B_re      = (const float*)d_in[4];
    const float* B_im      = (const float*)d_in[5];
    const float* C_re      = (const float*)d_in[6];
    const float* C_im      = (const float*)d_in[7];
    const float* D         = (const float*)d_in[8];
    float* out = (float*)d_out;

    // workspace layout (float2 complex):
    //   states : ROWS*STATE_F          = 134,217,728 B
    //   ends   : BATCH*NCHUNK*STATE_F  =   1,048,576 B
    //   lampow : CHUNK*STATE_F         =     262,144 B
    size_t need = ((size_t)ROWS * STATE_F + (size_t)BATCH * NCHUNK * STATE_F +
                   (size_t)CHUNK * STATE_F) * sizeof(float2);
    if (ws_size < need) return;  // cannot run without scratch; fail loudly via absmax

    float2* states = (float2*)d_ws;
    float2* ends   = states + (size_t)ROWS * STATE_F;
    float2* lampow = ends + (size_t)BATCH * NCHUNK * STATE_F;

    k0_lampow<<<1, 256, 0, stream>>>(nu_log, theta_log, lampow);
    k1_bu<<<ROWS / 16, 256, 0, stream>>>(x, B_re, B_im, gamma_log, states);
    k2a_scan<<<BATCH * NCHUNK, 256, 0, stream>>>(nu_log, theta_log, states, ends);
    k2b_chain<<<BATCH, 256, 0, stream>>>(nu_log, theta_log, ends);
    k3_out<<<ROWS / 16, 256, 0, stream>>>(x, C_re, C_im, D, states, ends, lampow, out);
}

// Round 2
// 124.036 us; speedup vs baseline: 3.8370x; 3.8370x over previous
//
#include <hip/hip_runtime.h>
#include <hip/hip_bf16.h>

#define BATCH 8
#define T 8192
#define IN_F 128
#define OUT_F 128
#define STATE_F 256
#define CHUNK 128
#define NCHUNK 64
#define ROWS 65536

typedef __attribute__((ext_vector_type(8))) short bf16x8;
typedef __attribute__((ext_vector_type(4))) float f32x4;

__device__ __forceinline__ float bflo(unsigned u) { return __uint_as_float(u << 16); }
__device__ __forceinline__ float bfhi(unsigned u) { return __uint_as_float(u & 0xffff0000u); }
__device__ __forceinline__ unsigned f2bfu(float f) {
    unsigned u = __float_as_uint(f);
    return (u + 0x7fffu + ((u >> 16) & 1u)) >> 16;
}
__device__ __forceinline__ unsigned packbf(float lo, float hi) {
    return f2bfu(lo) | (f2bfu(hi) << 16);
}

// ---------------------------------------------------------------------------
// kcvt: x fp32 -> bf16 (row-major [ROWS][128])
__global__ __launch_bounds__(256) void kcvt(const float* __restrict__ x,
                                            unsigned short* __restrict__ xbf) {
    int i0 = blockIdx.x * 256 + threadIdx.x;
#pragma unroll
    for (int it = 0; it < 4; ++it) {
        size_t g = (size_t)i0 + (size_t)it * 262144;  // 8-float groups, total 1048576
        const float4* s = (const float4*)(x + g * 8);
        float4 v0 = s[0], v1 = s[1];
        uint4 o;
        o.x = packbf(v0.x, v0.y); o.y = packbf(v0.z, v0.w);
        o.z = packbf(v1.x, v1.y); o.w = packbf(v1.z, v1.w);
        *(uint4*)(xbf + g * 8) = o;
    }
}

// ---------------------------------------------------------------------------
// k0a: lampow[j][n] = Lambda[n]^(j+1), j in [0,128)  (fp32 complex)
__global__ void k0a_lampow(const float* __restrict__ nu_log,
                           const float* __restrict__ theta_log,
                           float2* __restrict__ lampow) {
    int n = threadIdx.x;
    float lm = expf(-expf(nu_log[n]));
    float th = expf(theta_log[n]);
    float lr = lm * cosf(th), li = lm * sinf(th);
    float pr = lr, pi = li;
    for (int j = 0; j < CHUNK; ++j) {
        lampow[j * STATE_F + n] = make_float2(pr, pi);
        float t = fmaf(pr, lr, -pi * li);
        pi = fmaf(pr, li, pi * lr);
        pr = t;
    }
}

// ---------------------------------------------------------------------------
// k0b: pack W1 (512x128) A-fragments for k1.  Row n'=2n -> gamma*B_re[n],
// n'=2n+1 -> gamma*B_im[n].  Frag order: (mt,ks) -> lane l -> 8 bf16 with
// k = ks*32 + (l>>4)*8 + j,  n' = mt*16 + (l&15).
__global__ __launch_bounds__(256) void k0b_w1p(const float* __restrict__ B_re,
                                               const float* __restrict__ B_im,
                                               const float* __restrict__ gamma_log,
                                               unsigned short* __restrict__ W1p) {
    int tid = blockIdx.x * 256 + threadIdx.x;   // 0..8191
    int frag = tid >> 6, l = tid & 63;
    int mt = frag >> 2, ks = frag & 3;
    int np = mt * 16 + (l & 15);
    int k0 = ks * 32 + (l >> 4) * 8;
    int s = np >> 1;
    float g = expf(gamma_log[s]);
    const float* src = ((np & 1) ? B_im : B_re) + s * IN_F + k0;
    float4 a = *(const float4*)src, b = *(const float4*)(src + 4);
    uint4 o;
    o.x = packbf(a.x * g, a.y * g); o.y = packbf(a.z * g, a.w * g);
    o.z = packbf(b.x * g, b.y * g); o.w = packbf(b.z * g, b.w * g);
    *(uint4*)(W1p + (size_t)tid * 8) = o;
}

// ---------------------------------------------------------------------------
// k0c: pack W3 (128x640) B-fragments for k3: [C_re | -C_im | D].
// Frag order: (ct,ks) -> lane l: o = ct*16+(l&15), k = ks*32+(l>>4)*8+j.
__global__ __launch_bounds__(256) void k0c_w3p(const float* __restrict__ C_re,
                                               const float* __restrict__ C_im,
                                               const float* __restrict__ D,
                                               unsigned short* __restrict__ W3p) {
    int tid = blockIdx.x * 256 + threadIdx.x;   // 0..10239
    int frag = tid >> 6, l = tid & 63;
    int ct = frag / 20, ks = frag % 20;
    int o = ct * 16 + (l & 15);
    int k0 = ks * 32 + (l >> 4) * 8;
    const float* src;
    float sgn = 1.f;
    if (k0 < 256) src = C_re + o * STATE_F + k0;
    else if (k0 < 512) { src = C_im + o * STATE_F + (k0 - 256); sgn = -1.f; }
    else src = D + o * IN_F + (k0 - 512);
    float4 a = *(const float4*)src, b = *(const float4*)(src + 4);
    uint4 w;
    w.x = packbf(a.x * sgn, a.y * sgn); w.y = packbf(a.z * sgn, a.w * sgn);
    w.z = packbf(b.x * sgn, b.y * sgn); w.w = packbf(b.z * sgn, b.w * sgn);
    *(uint4*)(W3p + (size_t)tid * 8) = w;
}

// ---------------------------------------------------------------------------
// k1: transposed MFMA GEMM  D[n'][t] = sum_k W1[n'][k] * xbf[t][k].
// Block: 64 t-rows, full 512 n'.  Wave w: mt in [w*8,w*8+8), tt 0..3.
// Epilogue packs (re,im) bf16 pairs -> Bu[t][n] (uint per state).
__global__ __launch_bounds__(256, 2) void k1_bu(const short* __restrict__ xbf,
                                                const short* __restrict__ W1p,
                                                unsigned* __restrict__ Bu) {
    int tid = threadIdx.x;
    int wid = tid >> 6, l = tid & 63;
    int row0 = blockIdx.x * 64;
    const bf16x8* wp = (const bf16x8*)W1p;
    const bf16x8* xp = (const bf16x8*)xbf;

    f32x4 acc[8][4];
#pragma unroll
    for (int i = 0; i < 8; ++i)
#pragma unroll
        for (int t = 0; t < 4; ++t) acc[i][t] = (f32x4){0.f, 0.f, 0.f, 0.f};

#pragma unroll
    for (int ks = 0; ks < 4; ++ks) {
        bf16x8 b[4];
#pragma unroll
        for (int tt = 0; tt < 4; ++tt) {
            int t = row0 + tt * 16 + (l & 15);
            b[tt] = xp[(size_t)t * 16 + ks * 4 + (l >> 4)];
        }
#pragma unroll
        for (int i = 0; i < 8; ++i) {
            int mt = wid * 8 + i;
            bf16x8 a = wp[(size_t)(mt * 4 + ks) * 64 + l];
#pragma unroll
            for (int tt = 0; tt < 4; ++tt)
                acc[i][tt] = __builtin_amdgcn_mfma_f32_16x16x32_bf16(a, b[tt], acc[i][tt], 0, 0, 0);
        }
    }
    // epilogue: rows n' = mt*16 + (l>>4)*4 + r  ->  states n0=mt*8+(l>>4)*2, n0+1
#pragma unroll
    for (int i = 0; i < 8; ++i) {
        int n0 = (wid * 8 + i) * 8 + (l >> 4) * 2;
#pragma unroll
        for (int tt = 0; tt < 4; ++tt) {
            int t = row0 + tt * 16 + (l & 15);
            uint2 w;
            w.x = packbf(acc[i][tt][0], acc[i][tt][1]);  // re,im of n0
            w.y = packbf(acc[i][tt][2], acc[i][tt][3]);  // re,im of n0+1
            *(uint2*)(Bu + (size_t)t * STATE_F + n0) = w;
        }
    }
}

// ---------------------------------------------------------------------------
// k2a: in-place chunk scan on packed bf16 states (fp32 accumulator),
// records fp32 chunk-end states.
__global__ __launch_bounds__(256) void k2a_scan(const float* __restrict__ nu_log,
                                                const float* __restrict__ theta_log,
                                                unsigned* __restrict__ Bu,
                                                float2* __restrict__ ends) {
    int n = threadIdx.x;
    int b = blockIdx.x >> 6, c = blockIdx.x & 63;
    float lm = expf(-expf(nu_log[n]));
    float th = expf(theta_log[n]);
    float lr = lm * cosf(th), li = lm * sinf(th);
    float sr = 0.f, si = 0.f;
    unsigned* p = Bu + (((size_t)b * T + (size_t)c * CHUNK) * STATE_F + n);
#pragma unroll 8
    for (int j = 0; j < CHUNK; ++j) {
        unsigned u = p[(size_t)j * STATE_F];
        float br = bflo(u), bi = bfhi(u);
        float nr = fmaf(lr, sr, fmaf(-li, si, br));
        float ni = fmaf(lr, si, fmaf(li, sr, bi));
        sr = nr; si = ni;
        p[(size_t)j * STATE_F] = packbf(sr, si);
    }
    ends[((size_t)(b * NCHUNK + c)) * STATE_F + n] = make_float2(sr, si);
}

// ---------------------------------------------------------------------------
// k2b: scan over chunk-final states (Lambda^128 via 7 squarings), in place.
__global__ void k2b_chain(const float* __restrict__ nu_log,
                          const float* __restrict__ theta_log,
                          float2* __restrict__ ends) {
    int n = threadIdx.x;
    int b = blockIdx.x;
    float lm = expf(-expf(nu_log[n]));
    float th = expf(theta_log[n]);
    float Lr = lm * cosf(th), Li = lm * sinf(th);
#pragma unroll
    for (int i = 0; i < 7; ++i) {  // Lambda^128
        float t = Lr * Lr - Li * Li;
        Li = 2.f * Lr * Li;
        Lr = t;
    }
    float sr = 0.f, si = 0.f;
    float2* p = ends + (size_t)b * NCHUNK * STATE_F + n;
    for (int c = 0; c < NCHUNK; ++c) {
        float2 e = p[(size_t)c * STATE_F];
        float nr = fmaf(Lr, sr, fmaf(-Li, si, e.x));
        float ni = fmaf(Lr, si, fmaf(Li, sr, e.y));
        sr = nr; si = ni;
        p[(size_t)c * STATE_F] = make_float2(sr, si);
    }
}

// ---------------------------------------------------------------------------
// k3: fused fixup + output GEMM via MFMA.
// A (LDS, 32 rows x 640 bf16, XOR-swizzled 16B blocks) = [S_re | S_im | x].
// B = W3p prepacked.  out[t][o] fp32.
__global__ __launch_bounds__(256) void k3_out(const short* __restrict__ xbf,
                                              const short* __restrict__ W3p,
                                              const unsigned* __restrict__ Bu,
                                              const float2* __restrict__ ends,
                                              const float2* __restrict__ lampow,
                                              float* __restrict__ out) {
    __shared__ short A[32 * 640];  // 40 KB
    int tid = threadIdx.x;
    int l = tid & 63, wid = tid >> 6;
    int row0 = blockIdx.x * 32;
    int b = row0 >> 13;
    int t0 = row0 & (T - 1);
    int c = t0 >> 7;
    int j0 = t0 & (CHUNK - 1);

    // ---- stage x tile: cols 512..639 (16B blocks 64..79)
    const bf16x8* xp = (const bf16x8*)xbf;
#pragma unroll
    for (int i = 0; i < 2; ++i) {
        int idx = i * 256 + tid;
        int row = idx >> 4, seg = idx & 15;
        int blk = 64 + (seg ^ (row & 7));
        *(bf16x8*)&A[row * 640 + blk * 8] = xp[(size_t)(row0 + row) * 16 + seg];
    }
    // ---- stage states (fixup in fp32, split into re/im planes)
    {
        int half = tid >> 7, tn = tid & 127;
        int n0 = tn * 2;
        float c0r = 0.f, c0i = 0.f, c1r = 0.f, c1i = 0.f;
        if (c > 0) {
            float4 e = *(const float4*)&ends[((size_t)(b * NCHUNK + c - 1)) * STATE_F + n0];
            c0r = e.x; c0i = e.y; c1r = e.z; c1i = e.w;
        }
#pragma unroll 4
        for (int r8 = 0; r8 < 16; ++r8) {
            int r = half * 16 + r8;
            uint2 s2 = *(const uint2*)&Bu[(size_t)(row0 + r) * STATE_F + n0];
            float s0r = bflo(s2.x), s0i = bfhi(s2.x);
            float s1r = bflo(s2.y), s1i = bfhi(s2.y);
            if (c > 0) {
                float4 pw = *(const float4*)&lampow[(j0 + r) * STATE_F + n0];
                s0r = fmaf(pw.x, c0r, fmaf(-pw.y, c0i, s0r));
                s0i = fmaf(pw.x, c0i, fmaf(pw.y, c0r, s0i));
                s1r = fmaf(pw.z, c1r, fmaf(-pw.w, c1i, s1r));
                s1i = fmaf(pw.z, c1i, fmaf(pw.w, c1r, s1i));
            }
            int blk = (n0 >> 3) ^ (r & 7);
            int base = r * 640 + blk * 8 + (n0 & 7);
            *(unsigned*)&A[base] = packbf(s0r, s1r);             // re plane
            *(unsigned*)&A[base + 32 * 8] = packbf(s0i, s1i);    // im plane (+blocks 32)
        }
    }
    __syncthreads();

    // ---- GEMM: 20 ksteps, wave handles ct = {2w, 2w+1}, mt = 0..1
    const bf16x8* wp = (const bf16x8*)W3p;
    int ct0 = wid * 2;
    f32x4 acc[2][2];
#pragma unroll
    for (int m = 0; m < 2; ++m)
#pragma unroll
        for (int cc = 0; cc < 2; ++cc) acc[m][cc] = (f32x4){0.f, 0.f, 0.f, 0.f};

#pragma unroll 4
    for (int ks = 0; ks < 20; ++ks) {
        bf16x8 a[2];
#pragma unroll
        for (int m = 0; m < 2; ++m) {
            int r = m * 16 + (l & 15);
            int kb = ks * 4 + (l >> 4);
            int blk = kb ^ (r & 7);
            a[m] = *(const bf16x8*)&A[r * 640 + blk * 8];
        }
        bf16x8 bf[2];
#pragma unroll
        for (int cc = 0; cc < 2; ++cc)
            bf[cc] = wp[(size_t)((ct0 + cc) * 20 + ks) * 64 + l];
#pragma unroll
        for (int m = 0; m < 2; ++m)
#pragma unroll
            for (int cc = 0; cc < 2; ++cc)
                acc[m][cc] = __builtin_amdgcn_mfma_f32_16x16x32_bf16(a[m], bf[cc], acc[m][cc], 0, 0, 0);
    }
    // ---- epilogue
#pragma unroll
    for (int m = 0; m < 2; ++m)
#pragma unroll
        for (int cc = 0; cc < 2; ++cc)
#pragma unroll
            for (int r = 0; r < 4; ++r) {
                int t = row0 + m * 16 + (l >> 4) * 4 + r;
                int o = (ct0 + cc) * 16 + (l & 15);
                out[(size_t)t * OUT_F + o] = acc[m][cc][r];
            }
}

// ---------------------------------------------------------------------------
extern "C" void kernel_launch(void* const* d_in, const int* in_sizes, int n_in,
                              void* d_out, int out_size, void* d_ws, size_t ws_size,
                              hipStream_t stream) {
    const float* x         = (const float*)d_in[0];
    const float* nu_log    = (const float*)d_in[1];
    const float* theta_log = (const float*)d_in[2];
    const float* gamma_log = (const float*)d_in[3];
    const float* B_re      = (const float*)d_in[4];
    const float* B_im      = (const float*)d_in[5];
    const float* C_re      = (const float*)d_in[6];
    const float* C_im      = (const float*)d_in[7];
    const float* D         = (const float*)d_in[8];
    float* out = (float*)d_out;

    char* ws = (char*)d_ws;
    // layout (bytes):
    unsigned*       Bu     = (unsigned*)ws;                         // 67,108,864
    unsigned short* xbf    = (unsigned short*)(ws + 67108864);      // 16,777,216
    float2*         ends   = (float2*)(ws + 83886080);              //  1,048,576
    float2*         lampow = (float2*)(ws + 84934656);              //    262,144
    unsigned short* W1p    = (unsigned short*)(ws + 85196800);      //    131,072
    unsigned short* W3p    = (unsigned short*)(ws + 85327872);      //    163,840
    if (ws_size < (size_t)85491712) return;

    kcvt<<<1024, 256, 0, stream>>>(x, (unsigned short*)xbf);
    k0a_lampow<<<1, 256, 0, stream>>>(nu_log, theta_log, lampow);
    k0b_w1p<<<32, 256, 0, stream>>>(B_re, B_im, gamma_log, W1p);
    k0c_w3p<<<40, 256, 0, stream>>>(C_re, C_im, D, W3p);
    k1_bu<<<ROWS / 64, 256, 0, stream>>>((const short*)xbf, (const short*)W1p, Bu);
    k2a_scan<<<BATCH * NCHUNK, 256, 0, stream>>>(nu_log, theta_log, Bu, ends);
    k2b_chain<<<BATCH, 256, 0, stream>>>(nu_log, theta_log, ends);
    k3_out<<<ROWS / 32, 256, 0, stream>>>((const short*)xbf, (const short*)W3p,
                                          Bu, ends, lampow, out);
}

// Round 3
// 87.367 us; speedup vs baseline: 5.4475x; 1.4197x over previous
//
#include <hip/hip_runtime.h>
#include <hip/hip_bf16.h>

#define BATCH 8
#define T 8192
#define IN_F 128
#define OUT_F 128
#define STATE_F 256
#define CHUNK 64
#define NCHUNK 128
#define ROWS 65536

typedef __attribute__((ext_vector_type(8))) short bf16x8;
typedef __attribute__((ext_vector_type(4))) float f32x4;

__device__ __forceinline__ float bflo(unsigned u) { return __uint_as_float(u << 16); }
__device__ __forceinline__ float bfhi(unsigned u) { return __uint_as_float(u & 0xffff0000u); }
__device__ __forceinline__ unsigned packbf2(float lo, float hi) {
    __hip_bfloat162 h = __float22bfloat162_rn(make_float2(lo, hi));
    union { __hip_bfloat162 h; unsigned u; } cv; cv.h = h;
    return cv.u;
}

// ---------------------------------------------------------------------------
// k0a: lampow[j][n] = Lambda[n]^(j+1), j in [0,64)
__global__ void k0a_lampow(const float* __restrict__ nu_log,
                           const float* __restrict__ theta_log,
                           float2* __restrict__ lampow) {
    int n = threadIdx.x;
    float lm = expf(-expf(nu_log[n]));
    float th = expf(theta_log[n]);
    float lr = lm * cosf(th), li = lm * sinf(th);
    float pr = lr, pi = li;
    for (int j = 0; j < CHUNK; ++j) {
        lampow[j * STATE_F + n] = make_float2(pr, pi);
        float t = fmaf(pr, lr, -pi * li);
        pi = fmaf(pr, li, pi * lr);
        pr = t;
    }
}

// ---------------------------------------------------------------------------
// k0b: pack W1 (512x128) A-fragments. Row n'=2n -> gamma*B_re[n], 2n+1 -> gamma*B_im[n].
// Frag (mt,ks), lane l: n' = mt*16+(l&15), k = ks*32+(l>>4)*8+j.
__global__ __launch_bounds__(256) void k0b_w1p(const float* __restrict__ B_re,
                                               const float* __restrict__ B_im,
                                               const float* __restrict__ gamma_log,
                                               unsigned short* __restrict__ W1p) {
    int tid = blockIdx.x * 256 + threadIdx.x;   // 0..8191
    int frag = tid >> 6, l = tid & 63;
    int mt = frag >> 2, ks = frag & 3;
    int np = mt * 16 + (l & 15);
    int k0 = ks * 32 + (l >> 4) * 8;
    int s = np >> 1;
    float g = expf(gamma_log[s]);
    const float* src = ((np & 1) ? B_im : B_re) + s * IN_F + k0;
    float4 a = *(const float4*)src, b = *(const float4*)(src + 4);
    uint4 o;
    o.x = packbf2(a.x * g, a.y * g); o.y = packbf2(a.z * g, a.w * g);
    o.z = packbf2(b.x * g, b.y * g); o.w = packbf2(b.z * g, b.w * g);
    *(uint4*)(W1p + (size_t)tid * 8) = o;
}

// ---------------------------------------------------------------------------
// k0c: pack W3 (128x640) B-fragments: [C_re | -C_im | D].
__global__ __launch_bounds__(256) void k0c_w3p(const float* __restrict__ C_re,
                                               const float* __restrict__ C_im,
                                               const float* __restrict__ D,
                                               unsigned short* __restrict__ W3p) {
    int tid = blockIdx.x * 256 + threadIdx.x;   // 0..10239
    int frag = tid >> 6, l = tid & 63;
    int ct = frag / 20, ks = frag % 20;
    int o = ct * 16 + (l & 15);
    int k0 = ks * 32 + (l >> 4) * 8;
    const float* src;
    float sgn = 1.f;
    if (k0 < 256) src = C_re + o * STATE_F + k0;
    else if (k0 < 512) { src = C_im + o * STATE_F + (k0 - 256); sgn = -1.f; }
    else src = D + o * IN_F + (k0 - 512);
    float4 a = *(const float4*)src, b = *(const float4*)(src + 4);
    uint4 w;
    w.x = packbf2(a.x * sgn, a.y * sgn); w.y = packbf2(a.z * sgn, a.w * sgn);
    w.z = packbf2(b.x * sgn, b.y * sgn); w.w = packbf2(b.z * sgn, b.w * sgn);
    *(uint4*)(W3p + (size_t)tid * 8) = w;
}

// ---------------------------------------------------------------------------
// k1s: fused GEMM + chunk scan. One block = one scan chunk (64 t-rows).
// 512 threads (8 waves). Wave w: n' slice [w*64, w*64+64).
// Phase A: x fp32 -> bf16 LDS tile (swizzled). Phase B: MFMA GEMM ->
// packed bf16 states in swizzled LDS. Phase C: in-LDS sequential scan
// (fp32 carry). Phase D: write scanned states + chunk-end states.
__global__ __launch_bounds__(512, 2) void k1s(const float* __restrict__ x,
                                              const short* __restrict__ W1p,
                                              const float* __restrict__ nu_log,
                                              const float* __restrict__ theta_log,
                                              unsigned* __restrict__ states,
                                              float2* __restrict__ ends) {
    __shared__ unsigned S[CHUNK * STATE_F];  // 64 KB
    __shared__ short XT[CHUNK * IN_F];       // 16 KB
    int tid = threadIdx.x;
    int l = tid & 63, wid = tid >> 6;
    int bc = blockIdx.x;                     // b*NCHUNK + c
    size_t row0 = (size_t)bc * CHUNK;

    // ---- Phase A: stage x tile (each element converted once)
    {
        int row = tid >> 3, seg = tid & 7;   // 64 rows x 8 segs of 16 floats
        const float4* xp = (const float4*)(x + (row0 + row) * IN_F + seg * 16);
        float4 a = xp[0], b = xp[1], c2 = xp[2], d = xp[3];
        uint4 w0, w1;
        w0.x = packbf2(a.x, a.y); w0.y = packbf2(a.z, a.w);
        w0.z = packbf2(b.x, b.y); w0.w = packbf2(b.z, b.w);
        w1.x = packbf2(c2.x, c2.y); w1.y = packbf2(c2.z, c2.w);
        w1.z = packbf2(d.x, d.y);  w1.w = packbf2(d.z, d.w);
        int blk0 = (seg * 2) ^ (row & 7);
        int blk1 = (seg * 2 + 1) ^ (row & 7);
        short* dst = XT + row * IN_F;
        *(uint4*)(dst + blk0 * 8) = w0;
        *(uint4*)(dst + blk1 * 8) = w1;
    }
    __syncthreads();

    // ---- Phase B: GEMM
    const bf16x8* wp = (const bf16x8*)W1p;
    f32x4 acc[4][4];
#pragma unroll
    for (int i = 0; i < 4; ++i)
#pragma unroll
        for (int tt = 0; tt < 4; ++tt) acc[i][tt] = (f32x4){0.f, 0.f, 0.f, 0.f};

#pragma unroll
    for (int ks = 0; ks < 4; ++ks) {
        bf16x8 b[4];
#pragma unroll
        for (int tt = 0; tt < 4; ++tt) {
            int row = tt * 16 + (l & 15);
            int kb = ks * 4 + (l >> 4);
            b[tt] = *(const bf16x8*)&XT[row * IN_F + (kb ^ (row & 7)) * 8];
        }
#pragma unroll
        for (int i = 0; i < 4; ++i) {
            bf16x8 a = wp[(size_t)((wid * 4 + i) * 4 + ks) * 64 + l];
#pragma unroll
            for (int tt = 0; tt < 4; ++tt)
                acc[i][tt] = __builtin_amdgcn_mfma_f32_16x16x32_bf16(a, b[tt], acc[i][tt], 0, 0, 0);
        }
    }
    // epilogue: packed (re,im) pairs into swizzled LDS
#pragma unroll
    for (int i = 0; i < 4; ++i) {
#pragma unroll
        for (int tt = 0; tt < 4; ++tt) {
            int n0 = (wid * 4 + i) * 8 + (l >> 4) * 2;
            int t = tt * 16 + (l & 15);
            uint2 v;
            v.x = packbf2(acc[i][tt][0], acc[i][tt][1]);
            v.y = packbf2(acc[i][tt][2], acc[i][tt][3]);
            *(uint2*)&S[t * STATE_F + (n0 ^ ((t & 15) << 1))] = v;
        }
    }
    __syncthreads();

    // ---- Phase C: sequential scan in LDS (thread n, fp32 carry)
    if (tid < STATE_F) {
        int n = tid;
        float lm = expf(-expf(nu_log[n]));
        float th = expf(theta_log[n]);
        float lr = lm * cosf(th), li = lm * sinf(th);
        float sr = 0.f, si = 0.f;
#pragma unroll 8
        for (int t = 0; t < CHUNK; ++t) {
            int idx = t * STATE_F + (n ^ ((t & 15) << 1));
            unsigned u = S[idx];
            float br = bflo(u), bi = bfhi(u);
            float nr = fmaf(lr, sr, fmaf(-li, si, br));
            float ni = fmaf(lr, si, fmaf(li, sr, bi));
            sr = nr; si = ni;
            S[idx] = packbf2(sr, si);
        }
        ends[(size_t)bc * STATE_F + n] = make_float2(sr, si);
    }
    __syncthreads();

    // ---- Phase D: write out scanned states (coalesced uint2)
#pragma unroll
    for (int j = 0; j < 16; ++j) {
        int idx = j * 512 + tid;
        int row = idx >> 7, p2 = idx & 127;
        int n0 = p2 * 2;
        uint2 v = *(uint2*)&S[row * STATE_F + (n0 ^ ((row & 15) << 1))];
        *(uint2*)&states[(row0 + row) * STATE_F + n0] = v;
    }
}

// ---------------------------------------------------------------------------
// k2b: scan over chunk-final states (Lambda^64 via 6 squarings), in place.
__global__ void k2b_chain(const float* __restrict__ nu_log,
                          const float* __restrict__ theta_log,
                          float2* __restrict__ ends) {
    int n = threadIdx.x;
    int b = blockIdx.x;
    float lm = expf(-expf(nu_log[n]));
    float th = expf(theta_log[n]);
    float Lr = lm * cosf(th), Li = lm * sinf(th);
#pragma unroll
    for (int i = 0; i < 6; ++i) {  // Lambda^64
        float t = Lr * Lr - Li * Li;
        Li = 2.f * Lr * Li;
        Lr = t;
    }
    float sr = 0.f, si = 0.f;
    float2* p = ends + (size_t)b * NCHUNK * STATE_F + n;
    for (int c = 0; c < NCHUNK; ++c) {
        float2 e = p[(size_t)c * STATE_F];
        float nr = fmaf(Lr, sr, fmaf(-Li, si, e.x));
        float ni = fmaf(Lr, si, fmaf(Li, sr, e.y));
        sr = nr; si = ni;
        p[(size_t)c * STATE_F] = make_float2(sr, si);
    }
}

// ---------------------------------------------------------------------------
// k3: fused fixup + output GEMM via MFMA. 512 threads (8 waves), 32-row tile.
// A (LDS, 32 x 640 bf16, XOR-swizzled 16B blocks) = [S_re | S_im | x].
__global__ __launch_bounds__(512) void k3_out(const float* __restrict__ x,
                                              const short* __restrict__ W3p,
                                              const unsigned* __restrict__ states,
                                              const float2* __restrict__ ends,
                                              const float2* __restrict__ lampow,
                                              float* __restrict__ out) {
    __shared__ short A[32 * 640];  // 40 KB
    int tid = threadIdx.x;
    int l = tid & 63, wid = tid >> 6;
    int row0 = blockIdx.x * 32;
    int b = row0 >> 13;
    int t0 = row0 & (T - 1);
    int c = t0 >> 6;
    int j0 = t0 & (CHUNK - 1);

    // ---- preload all state pairs for this thread (async-split: loads first)
    int tn = tid & 127, grp = tid >> 7;
    int n0 = tn * 2;
    uint2 sv[8];
#pragma unroll
    for (int r8 = 0; r8 < 8; ++r8)
        sv[r8] = *(const uint2*)&states[(size_t)(row0 + grp * 8 + r8) * STATE_F + n0];

    // ---- stage x tile (fp32 -> bf16, swizzled): cols 512..639
    {
        int row = tid >> 4, seg = tid & 15;
        const float4* xp = (const float4*)(x + (size_t)(row0 + row) * IN_F + seg * 8);
        float4 a = xp[0], bb = xp[1];
        uint4 w;
        w.x = packbf2(a.x, a.y); w.y = packbf2(a.z, a.w);
        w.z = packbf2(bb.x, bb.y); w.w = packbf2(bb.z, bb.w);
        *(uint4*)&A[row * 640 + (64 + (seg ^ (row & 7))) * 8] = w;
    }

    // ---- fixup + write state planes
    {
        float c0r = 0.f, c0i = 0.f, c1r = 0.f, c1i = 0.f;
        if (c > 0) {
            float4 e = *(const float4*)&ends[((size_t)(b * NCHUNK + c - 1)) * STATE_F + n0];
            c0r = e.x; c0i = e.y; c1r = e.z; c1i = e.w;
        }
#pragma unroll
        for (int r8 = 0; r8 < 8; ++r8) {
            int r = grp * 8 + r8;
            float s0r = bflo(sv[r8].x), s0i = bfhi(sv[r8].x);
            float s1r = bflo(sv[r8].y), s1i = bfhi(sv[r8].y);
            if (c > 0) {
                float4 pw = *(const float4*)&lampow[(j0 + r) * STATE_F + n0];
                s0r = fmaf(pw.x, c0r, fmaf(-pw.y, c0i, s0r));
                s0i = fmaf(pw.x, c0i, fmaf(pw.y, c0r, s0i));
                s1r = fmaf(pw.z, c1r, fmaf(-pw.w, c1i, s1r));
                s1i = fmaf(pw.z, c1i, fmaf(pw.w, c1r, s1i));
            }
            int blk = (n0 >> 3) ^ (r & 7);
            int base = r * 640 + blk * 8 + (n0 & 7);
            *(unsigned*)&A[base] = packbf2(s0r, s1r);         // re plane
            *(unsigned*)&A[base + 256] = packbf2(s0i, s1i);   // im plane (+32 blocks)
        }
    }
    __syncthreads();

    // ---- GEMM: wave wid -> ct = wid (out cols wid*16..+16), m = 0..1
    const bf16x8* wp = (const bf16x8*)W3p;
    int ct = wid;
    f32x4 acc[2];
    acc[0] = (f32x4){0.f, 0.f, 0.f, 0.f};
    acc[1] = (f32x4){0.f, 0.f, 0.f, 0.f};

#pragma unroll 4
    for (int ks = 0; ks < 20; ++ks) {
        bf16x8 bf = wp[(size_t)(ct * 20 + ks) * 64 + l];
#pragma unroll
        for (int m = 0; m < 2; ++m) {
            int rr = m * 16 + (l & 15);
            int kb = ks * 4 + (l >> 4);
            bf16x8 am = *(const bf16x8*)&A[rr * 640 + (kb ^ (rr & 7)) * 8];
            acc[m] = __builtin_amdgcn_mfma_f32_16x16x32_bf16(am, bf, acc[m], 0, 0, 0);
        }
    }
    // ---- epilogue
#pragma unroll
    for (int m = 0; m < 2; ++m)
#pragma unroll
        for (int r = 0; r < 4; ++r) {
            int t = row0 + m * 16 + (l >> 4) * 4 + r;
            int o = ct * 16 + (l & 15);
            out[(size_t)t * OUT_F + o] = acc[m][r];
        }
}

// ---------------------------------------------------------------------------
extern "C" void kernel_launch(void* const* d_in, const int* in_sizes, int n_in,
                              void* d_out, int out_size, void* d_ws, size_t ws_size,
                              hipStream_t stream) {
    const float* x         = (const float*)d_in[0];
    const float* nu_log    = (const float*)d_in[1];
    const float* theta_log = (const float*)d_in[2];
    const float* gamma_log = (const float*)d_in[3];
    const float* B_re      = (const float*)d_in[4];
    const float* B_im      = (const float*)d_in[5];
    const float* C_re      = (const float*)d_in[6];
    const float* C_im      = (const float*)d_in[7];
    const float* D         = (const float*)d_in[8];
    float* out = (float*)d_out;

    char* ws = (char*)d_ws;
    // layout (bytes):
    unsigned*       states = (unsigned*)ws;                         // 67,108,864
    float2*         ends   = (float2*)(ws + 67108864);              //  2,097,152
    float2*         lampow = (float2*)(ws + 69206016);              //    131,072
    unsigned short* W1p    = (unsigned short*)(ws + 69337088);      //    131,072
    unsigned short* W3p    = (unsigned short*)(ws + 69468160);      //    163,840
    if (ws_size < (size_t)69632000) return;

    k0a_lampow<<<1, 256, 0, stream>>>(nu_log, theta_log, lampow);
    k0b_w1p<<<32, 256, 0, stream>>>(B_re, B_im, gamma_log, W1p);
    k0c_w3p<<<40, 256, 0, stream>>>(C_re, C_im, D, W3p);
    k1s<<<BATCH * NCHUNK, 512, 0, stream>>>(x, (const short*)W1p, nu_log, theta_log,
                                            states, ends);
    k2b_chain<<<BATCH, 256, 0, stream>>>(nu_log, theta_log, ends);
    k3_out<<<ROWS / 32, 512, 0, stream>>>(x, (const short*)W3p, states, ends, lampow, out);
}